// Round 12
// baseline (142.765 us; speedup 1.0000x reference)
//
#include <hip/hip_runtime.h>
#include <math.h>

// Neural Additive Model: 256 per-feature MLPs 1->128->64->32->1 (ReLU), summed.
// B=8192, fp32 in/out.
//
// Exact rank-table decomposition: pre-relu h2[b,k] = x_b*Sw[r,k] + Sb[r,k],
// r = #(sorted layer-1 thresholds < x_b). Layer 3 on bf16 MFMA (A=W3^T, B=h2),
// layer 4 reduced in-register + 2 shfl_xor, one atomicAdd per element.
//
// Round 12 (gap analysis): total-minus-fused has been ~76 us since R5; R4
// showed graph launch overhead ~0, so transpose_x itself was ~70 us (20x its
// 8.4 MB of traffic). DELETE it:
//  * x read directly in the main loop (32 scattered 4-B loads/lane, hidden by
//    TLP; 16 consecutive features share each 64-B line -> L3 absorbs).
//  * grid 512 = (feature, batch-half): LDS 76.5 KB -> 2 blocks/CU = 32
//    waves/CU (was 1 block/CU = 50% cap). Phase A (table build) runs twice
//    per feature -- cheap, and paid back by 2x latency hiding.
//  * init_out returns as a ~2 us separate launch.

#define NF   256
#define NH1  128
#define NH2  64
#define NH3  32
#define NB   8192

#define NRANK 129
#define ROW4  17                      // uint4 per table row (64 pairs + pad, odd)
#define ROWU  (ROW4 * 4)              // 68 uint32 per row

typedef float    f32x4 __attribute__((ext_vector_type(4)));
typedef short    s16x8 __attribute__((ext_vector_type(8)));
typedef unsigned u32x4 __attribute__((ext_vector_type(4)));

// float -> bf16 bits, round-to-nearest-even (build phase)
__device__ __forceinline__ short f2bf(float f) {
    unsigned int u = __float_as_uint(f);
    u += 0x7FFFu + ((u >> 16) & 1u);
    return (short)(u >> 16);
}
// pack two non-negative floats to (bf16(h1)<<16)|bf16(h0), round-half-up
__device__ __forceinline__ unsigned pack2(float h0, float h1) {
    unsigned a = __float_as_uint(h1) + 0x8000u;
    unsigned b = __float_as_uint(h0) + 0x8000u;
    return __builtin_amdgcn_perm(a, b, 0x07060302u);  // hi16(a)<<16 | hi16(b)
}
// unpack packed (Sb<<16|Sw) and evaluate h2 = relu(x*Sw+Sb)
__device__ __forceinline__ float h2eval(unsigned u, float xv) {
    float sw = __uint_as_float(u << 16);
    float sb = __uint_as_float(u & 0xFFFF0000u);
    return fmaxf(fmaf(xv, sw, sb), 0.0f);
}

__global__ __launch_bounds__(256) void init_out_kernel(float* __restrict__ out,
                                                       const float* __restrict__ bias) {
    int i = blockIdx.x * 256 + threadIdx.x;
    if (i < NB) out[i] = bias[0];
}

// ---------------- fused: build table in LDS, then MFMA main loop ----------------
__global__ __launch_bounds__(1024, 2) void nam_fused(
    const float* __restrict__ x,      // [B][F], read strided (L3 absorbs reuse)
    const float* __restrict__ W1, const float* __restrict__ b1,
    const float* __restrict__ W2, const float* __restrict__ b2,
    const float* __restrict__ W3, const float* __restrict__ b3,
    const float* __restrict__ W4, const float* __restrict__ b4,
    float* __restrict__ out)
{
    __shared__ u32x4 SP4[NRANK * ROW4];    // 35.1 KB packed-bf16 (Sb<<16|Sw), rank-major
    __shared__ float w2s[NH1 * NH2];       // 32 KB  W2[f] staged (build phase only)
    __shared__ float tkey[NH1];            // sorted thresholds
    __shared__ int   tidx[NH1];
    __shared__ float w1s[NH1], b1s[NH1];
    __shared__ float Pbw[8][NH2], Pbb[8][NH2], Pdw[8][NH2], Pdb[8][NH2]; // 8 KB

    const int f    = blockIdx.x >> 1;      // feature
    const int half = blockIdx.x & 1;       // batch half (2 blocks/feature -> 2 blocks/CU)
    const int t = (int)threadIdx.x;
    unsigned* SPu = (unsigned*)SP4;

    // ======== Phase A: build the rank table in LDS (packed bf16) ========
    {
        const float4* w2g = (const float4*)(W2 + (size_t)f * NH1 * NH2);
        float4* w2l = (float4*)w2s;
        for (int i = t; i < NH1 * NH2 / 4; i += 1024) w2l[i] = w2g[i];
    }
    if (t < NH1) {
        float w  = W1[f * NH1 + t];
        float bb = b1[f * NH1 + t];
        w1s[t] = w; b1s[t] = bb;
        tkey[t] = (w != 0.0f) ? (-bb / w) : INFINITY;   // w==0: never toggled
        tidx[t] = t;
    }
    __syncthreads();

    // bitonic sort of 128 (key asc, payload idx); 64 comparators
    for (int size = 2; size <= NH1; size <<= 1) {
        for (int stride = size >> 1; stride > 0; stride >>= 1) {
            if (t < 64) {
                int pos = ((t / stride) * (stride << 1)) + (t % stride);
                int par = pos + stride;
                bool up = ((pos & size) == 0);
                float a = tkey[pos], c = tkey[par];
                int  ia = tidx[pos], ic = tidx[par];
                if ((a > c) == up) {
                    tkey[pos] = c; tkey[par] = a;
                    tidx[pos] = ic; tidx[par] = ia;
                }
            }
            __syncthreads();
        }
    }

    // chunked scan: 512 threads = (k = t&63) x (chunk c = t>>6, 16 j/ranks each)
    if (t < 512) {
        const int k = t & 63, c = t >> 6;
        float bw = 0.0f, bbp = 0.0f, dw = 0.0f, db = 0.0f;
        #pragma unroll 4
        for (int i = 0; i < 16; ++i) {
            int j = c * 16 + i;    // rank-0 base: w<0 active; w==0&&b>0 const-on
            float w = w1s[j], bv = b1s[j], w2v = w2s[j * NH2 + k];
            if (w < 0.0f) { bw = fmaf(w, w2v, bw); bbp = fmaf(bv, w2v, bbp); }
            else if (w == 0.0f && bv > 0.0f) { bbp = fmaf(bv, w2v, bbp); }
            int jj = tidx[c * 16 + i];   // toggle-delta partial
            float ww = w1s[jj], bv2 = b1s[jj], w2x = w2s[jj * NH2 + k];
            float s = (ww > 0.0f) ? 1.0f : ((ww < 0.0f) ? -1.0f : 0.0f);
            dw = fmaf(s * ww,  w2x, dw);
            db = fmaf(s * bv2, w2x, db);
        }
        Pbw[c][k] = bw; Pbb[c][k] = bbp; Pdw[c][k] = dw; Pdb[c][k] = db;
    }
    __syncthreads();
    if (t < 512) {
        const int k = t & 63, c = t >> 6;
        float accw = 0.0f;
        float accb = b2[f * NH2 + k];    // b2 seed (round-8 lesson)
        #pragma unroll
        for (int c2 = 0; c2 < 8; ++c2) { accw += Pbw[c2][k]; accb += Pbb[c2][k]; }
        for (int c2 = 0; c2 < c; ++c2) { accw += Pdw[c2][k]; accb += Pdb[c2][k]; }
        if (c == 0)
            SPu[k] = ((unsigned)(unsigned short)f2bf(accb) << 16)
                   | (unsigned short)f2bf(accw);            // rank-0 row
        #pragma unroll 4
        for (int i = 0; i < 16; ++i) {
            int r = c * 16 + i;
            int j = tidx[r];                       // uniform per chunk -> broadcast
            float w = w1s[j], bv = b1s[j], w2v = w2s[j * NH2 + k];
            float s = (w > 0.0f) ? 1.0f : ((w < 0.0f) ? -1.0f : 0.0f);
            accw = fmaf(s * w,  w2v, accw);
            accb = fmaf(s * bv, w2v, accb);
            SPu[(r + 1) * ROWU + k] = ((unsigned)(unsigned short)f2bf(accb) << 16)
                                    | (unsigned short)f2bf(accw);
        }
    }
    __syncthreads();

    // ======== Phase B: MFMA main loop (A = W3^T, B = h2) ========
    const int lane = t & 63, wv = t >> 6;   // 16 waves
    const int n = lane & 15, q = lane >> 4; // n = batch-in-tile (B) / ch (A-frag)

    // A-frags: A[m=lane&15][k=quad*8+j] = W3[k][ch]; ch tiles 0 and 16+
    const float* __restrict__ w3g = W3 + f * NH2 * NH3;
    s16x8 aT0lo, aT0hi, aT1lo, aT1hi;
    #pragma unroll
    for (int j = 0; j < 8; ++j) {
        int k = q * 8 + j;
        aT0lo[j] = f2bf(w3g[k * NH3 + n]);
        aT0hi[j] = f2bf(w3g[(k + 32) * NH3 + n]);
        aT1lo[j] = f2bf(w3g[k * NH3 + n + 16]);
        aT1hi[j] = f2bf(w3g[(k + 32) * NH3 + n + 16]);
    }
    // per-lane channel constants: rows q*4+i (acc0) and 16+q*4+i (acc1)
    float b3c[4], b3ch[4], w4c[4], w4ch[4];
    #pragma unroll
    for (int i = 0; i < 4; ++i) {
        b3c[i]  = b3[f * NH3 + q * 4 + i];
        b3ch[i] = b3[f * NH3 + 16 + q * 4 + i];
        w4c[i]  = W4[f * NH3 + q * 4 + i];
        w4ch[i] = W4[f * NH3 + 16 + q * 4 + i];
    }
    const float b4f = b4[f];

    #pragma unroll 1
    for (int round = 0; round < 16; ++round) {
        const int base = half * 4096 + (round * 16 + wv) * 16;  // 16-elem batch tile
        const int b = base + n;
        const float xv = x[(size_t)b * NF + f];   // strided; L3-served, TLP-hidden

        // rank = #(tkey < xv), branchless binary search (LDS)
        int r = 0;
        #pragma unroll
        for (int s = 64; s > 0; s >>= 1)
            if (tkey[r + s - 1] < xv) r += s;

        // gather lane's 16 packed pairs: k = q*8..+7 and 32+q*8..+7, row r
        const int ro = r * ROW4 + q * 2;
        u32x4 U0 = SP4[ro],     U1 = SP4[ro + 1];
        u32x4 U2 = SP4[ro + 8], U3 = SP4[ro + 9];

        // B-frags: B[k=quad*8+j][n=lane&15] = h2[batch n][k]
        u32x4 d0, d1;
        d0.x = pack2(h2eval(U0.x, xv), h2eval(U0.y, xv));
        d0.y = pack2(h2eval(U0.z, xv), h2eval(U0.w, xv));
        d0.z = pack2(h2eval(U1.x, xv), h2eval(U1.y, xv));
        d0.w = pack2(h2eval(U1.z, xv), h2eval(U1.w, xv));
        d1.x = pack2(h2eval(U2.x, xv), h2eval(U2.y, xv));
        d1.y = pack2(h2eval(U2.z, xv), h2eval(U2.w, xv));
        d1.z = pack2(h2eval(U3.x, xv), h2eval(U3.y, xv));
        d1.w = pack2(h2eval(U3.z, xv), h2eval(U3.w, xv));
        s16x8 bf0 = __builtin_bit_cast(s16x8, d0);
        s16x8 bf1 = __builtin_bit_cast(s16x8, d1);

        // layer 3: D[ch][batch] = W3^T x H2^T (+b3); lane: col=batch n, rows=ch q*4+i
        f32x4 acc0 = {b3c[0], b3c[1], b3c[2], b3c[3]};
        f32x4 acc1 = {b3ch[0], b3ch[1], b3ch[2], b3ch[3]};
        acc0 = __builtin_amdgcn_mfma_f32_16x16x32_bf16(aT0lo, bf0, acc0, 0, 0, 0);
        acc0 = __builtin_amdgcn_mfma_f32_16x16x32_bf16(aT0hi, bf1, acc0, 0, 0, 0);
        acc1 = __builtin_amdgcn_mfma_f32_16x16x32_bf16(aT1lo, bf0, acc1, 0, 0, 0);
        acc1 = __builtin_amdgcn_mfma_f32_16x16x32_bf16(aT1hi, bf1, acc1, 0, 0, 0);

        // layer 4: reduce over the lane's OWN 8 channels, then 2 shfls over q
        float p = fmaxf(acc0[0], 0.0f) * w4c[0] + fmaxf(acc1[0], 0.0f) * w4ch[0]
                + fmaxf(acc0[1], 0.0f) * w4c[1] + fmaxf(acc1[1], 0.0f) * w4ch[1]
                + fmaxf(acc0[2], 0.0f) * w4c[2] + fmaxf(acc1[2], 0.0f) * w4ch[2]
                + fmaxf(acc0[3], 0.0f) * w4c[3] + fmaxf(acc1[3], 0.0f) * w4ch[3];
        p += __shfl_xor(p, 16);
        p += __shfl_xor(p, 32);
        if (lane < 16) atomicAdd(&out[base + lane], p + b4f);
    }
}

extern "C" void kernel_launch(void* const* d_in, const int* in_sizes, int n_in,
                              void* d_out, int out_size, void* d_ws, size_t ws_size,
                              hipStream_t stream) {
    const float* x    = (const float*)d_in[0];
    const float* W1   = (const float*)d_in[1];
    const float* b1   = (const float*)d_in[2];
    const float* W2   = (const float*)d_in[3];
    const float* b2   = (const float*)d_in[4];
    const float* W3   = (const float*)d_in[5];
    const float* b3   = (const float*)d_in[6];
    const float* W4   = (const float*)d_in[7];
    const float* b4   = (const float*)d_in[8];
    const float* bias = (const float*)d_in[9];
    float* out = (float*)d_out;

    // d_out is poisoned before every launch: initialize to bias (atomics add onto it)
    init_out_kernel<<<NB / 256, 256, 0, stream>>>(out, bias);
    // grid 512 = (feature, batch-half): 2 blocks/CU, 32 waves/CU
    nam_fused<<<NF * 2, 1024, 0, stream>>>(x, W1, b1, W2, b2,
                                           W3, b3, W4, b4, out);
}

// Round 13
// 126.399 us; speedup vs baseline: 1.1295x; 1.1295x over previous
//
#include <hip/hip_runtime.h>
#include <math.h>

// Neural Additive Model: 256 per-feature MLPs 1->128->64->32->1 (ReLU), summed.
// B=8192, fp32 in/out.
//
// Exact rank-table decomposition: pre-relu h2[b,k] = x_b*Sw[r,k] + Sb[r,k],
// r = #(sorted layer-1 thresholds < x_b). Layer 3 on f16 MFMA (A=W3^T, B=h2),
// layer 4 reduced in-register + 2 shfl_xor, one atomicAdd per element.
//
// Round 13 (R12 lesson: bench = kernel + ~74 us FIXED harness overhead; only
// the fused kernel is addressable. Its budget: VALU ~36 us (h2 unpack/pack),
// LDS ~30 us, occupancy stuck at 16 waves/CU):
//  * Table stored as packed f16 PAIRS (Sw-pairs, Sb-pairs): h2 for 2 channels
//    = one v_pk_fma_f16 + one v_pk_max_f16, result IS the MFMA B-frag dword.
//    Deletes the 64-op unpack + 24-op pack per wave-round. MFMA -> _f16.
//    f16 has 3 more mantissa bits than bf16 -> absmax improves.
//  * W2 LDS staging dropped; build-scan reads W2 from global (coalesced 256-B
//    rows per 64-thread k-group, L1-cached). LDS 76.5 -> 45.6 KB ->
//    2 x 1024-thread blocks/CU fit with slack; launch_bounds(1024,8) pins
//    VGPR <= 64 so 32 waves/CU is reachable.

#define NF   256
#define NH1  128
#define NH2  64
#define NH3  32
#define NB   8192

#define NRANK 129
#define ROW4  17                      // uint4 per table row (64 dwords data + 4 pad)
#define ROWH  136                     // halfwords per row (68 dwords)

typedef float    f32x4 __attribute__((ext_vector_type(4)));
typedef unsigned u32x4 __attribute__((ext_vector_type(4)));
typedef _Float16 h16x2 __attribute__((ext_vector_type(2)));
typedef _Float16 h16x8 __attribute__((ext_vector_type(8)));

// h2 pair: relu(x*Sw + Sb) on 2 packed f16 channels -> one B-frag dword
__device__ __forceinline__ unsigned pkh2(unsigned sw, unsigned sb, h16x2 xh) {
    h16x2 r = __builtin_elementwise_fma(xh, __builtin_bit_cast(h16x2, sw),
                                            __builtin_bit_cast(h16x2, sb));
    h16x2 hz = {(_Float16)0.f, (_Float16)0.f};
    return __builtin_bit_cast(unsigned, __builtin_elementwise_max(r, hz));
}

__global__ __launch_bounds__(256) void init_out_kernel(float* __restrict__ out,
                                                       const float* __restrict__ bias) {
    int i = blockIdx.x * 256 + threadIdx.x;
    if (i < NB) out[i] = bias[0];
}

// ---------------- fused: build table in LDS, then MFMA main loop ----------------
__global__ __launch_bounds__(1024, 8) void nam_fused(
    const float* __restrict__ x,      // [B][F], strided reads (L3 absorbs reuse)
    const float* __restrict__ W1, const float* __restrict__ b1,
    const float* __restrict__ W2, const float* __restrict__ b2,
    const float* __restrict__ W3, const float* __restrict__ b3,
    const float* __restrict__ W4, const float* __restrict__ b4,
    float* __restrict__ out)
{
    __shared__ u32x4 SP4[NRANK * ROW4];    // 35.1 KB: per row, 32 Sw-pair dwords,
                                           //   32 Sb-pair dwords (f16), 4 pad
    __shared__ float tkey[NH1];            // sorted thresholds
    __shared__ int   tidx[NH1];
    __shared__ float w1s[NH1], b1s[NH1];
    __shared__ float Pbw[8][NH2], Pbb[8][NH2], Pdw[8][NH2], Pdb[8][NH2]; // 8 KB

    const int f    = blockIdx.x >> 1;      // feature
    const int half = blockIdx.x & 1;       // batch half
    const int t = (int)threadIdx.x;
    _Float16* SPh = (_Float16*)SP4;

    // ======== Phase A: build the rank table in LDS (packed f16 pairs) ========
    const float* __restrict__ gw2 = W2 + (size_t)f * NH1 * NH2;
    if (t < NH1) {
        float w  = W1[f * NH1 + t];
        float bb = b1[f * NH1 + t];
        w1s[t] = w; b1s[t] = bb;
        tkey[t] = (w != 0.0f) ? (-bb / w) : INFINITY;   // w==0: never toggled
        tidx[t] = t;
    }
    __syncthreads();

    // bitonic sort of 128 (key asc, payload idx); 64 comparators
    for (int size = 2; size <= NH1; size <<= 1) {
        for (int stride = size >> 1; stride > 0; stride >>= 1) {
            if (t < 64) {
                int pos = ((t / stride) * (stride << 1)) + (t % stride);
                int par = pos + stride;
                bool up = ((pos & size) == 0);
                float a = tkey[pos], c = tkey[par];
                int  ia = tidx[pos], ic = tidx[par];
                if ((a > c) == up) {
                    tkey[pos] = c; tkey[par] = a;
                    tidx[pos] = ic; tidx[par] = ia;
                }
            }
            __syncthreads();
        }
    }

    // chunked scan: 512 threads = (k = t&63) x (chunk c = t>>6, 16 j/ranks each)
    // W2 read from GLOBAL: per 64-thread k-group each row is a coalesced 256-B line.
    if (t < 512) {
        const int k = t & 63, c = t >> 6;
        float bw = 0.0f, bbp = 0.0f, dw = 0.0f, db = 0.0f;
        #pragma unroll 4
        for (int i = 0; i < 16; ++i) {
            int j = c * 16 + i;    // rank-0 base: w<0 active; w==0&&b>0 const-on
            float w = w1s[j], bv = b1s[j], w2v = gw2[j * NH2 + k];
            if (w < 0.0f) { bw = fmaf(w, w2v, bw); bbp = fmaf(bv, w2v, bbp); }
            else if (w == 0.0f && bv > 0.0f) { bbp = fmaf(bv, w2v, bbp); }
            int jj = tidx[c * 16 + i];   // toggle-delta partial
            float ww = w1s[jj], bv2 = b1s[jj], w2x = gw2[jj * NH2 + k];
            float s = (ww > 0.0f) ? 1.0f : ((ww < 0.0f) ? -1.0f : 0.0f);
            dw = fmaf(s * ww,  w2x, dw);
            db = fmaf(s * bv2, w2x, db);
        }
        Pbw[c][k] = bw; Pbb[c][k] = bbp; Pdw[c][k] = dw; Pdb[c][k] = db;
    }
    __syncthreads();
    if (t < 512) {
        const int k = t & 63, c = t >> 6;
        float accw = 0.0f;
        float accb = b2[f * NH2 + k];    // b2 seed (round-8 lesson)
        #pragma unroll
        for (int c2 = 0; c2 < 8; ++c2) { accw += Pbw[c2][k]; accb += Pbb[c2][k]; }
        for (int c2 = 0; c2 < c; ++c2) { accw += Pdw[c2][k]; accb += Pdb[c2][k]; }
        // layout per row: Sw halves [0..63], Sb halves [64..127], pad to 136
        if (c == 0) {
            SPh[k]      = (_Float16)accw;          // rank-0 row
            SPh[64 + k] = (_Float16)accb;
        }
        #pragma unroll 4
        for (int i = 0; i < 16; ++i) {
            int r = c * 16 + i;
            int j = tidx[r];                       // uniform per chunk -> broadcast
            float w = w1s[j], bv = b1s[j], w2v = gw2[j * NH2 + k];
            float s = (w > 0.0f) ? 1.0f : ((w < 0.0f) ? -1.0f : 0.0f);
            accw = fmaf(s * w,  w2v, accw);
            accb = fmaf(s * bv, w2v, accb);
            SPh[(r + 1) * ROWH + k]      = (_Float16)accw;
            SPh[(r + 1) * ROWH + 64 + k] = (_Float16)accb;
        }
    }
    __syncthreads();

    // ======== Phase B: MFMA main loop (A = W3^T, B = h2), f16 ========
    const int lane = t & 63, wv = t >> 6;   // 16 waves
    const int n = lane & 15, q = lane >> 4; // n = batch-in-tile / ch (A-frag)

    // A-frags: A[m=lane&15][k=quad*8+j] = W3[k][ch]; ch tiles 0 and 16+
    const float* __restrict__ w3g = W3 + f * NH2 * NH3;
    h16x8 aT0lo, aT0hi, aT1lo, aT1hi;
    #pragma unroll
    for (int j = 0; j < 8; ++j) {
        int k = q * 8 + j;
        aT0lo[j] = (_Float16)w3g[k * NH3 + n];
        aT0hi[j] = (_Float16)w3g[(k + 32) * NH3 + n];
        aT1lo[j] = (_Float16)w3g[k * NH3 + n + 16];
        aT1hi[j] = (_Float16)w3g[(k + 32) * NH3 + n + 16];
    }
    // per-lane channel constants: rows q*4+i (acc0) and 16+q*4+i (acc1)
    float b3c[4], b3ch[4], w4c[4], w4ch[4];
    #pragma unroll
    for (int i = 0; i < 4; ++i) {
        b3c[i]  = b3[f * NH3 + q * 4 + i];
        b3ch[i] = b3[f * NH3 + 16 + q * 4 + i];
        w4c[i]  = W4[f * NH3 + q * 4 + i];
        w4ch[i] = W4[f * NH3 + 16 + q * 4 + i];
    }
    const float b4f = b4[f];

    #pragma unroll 1
    for (int round = 0; round < 16; ++round) {
        const int base = half * 4096 + (round * 16 + wv) * 16;  // 16-elem batch tile
        const int b = base + n;
        const float xv = x[(size_t)b * NF + f];   // strided; L3-served, TLP-hidden

        // rank = #(tkey < xv), branchless binary search (LDS)
        int r = 0;
        #pragma unroll
        for (int s = 64; s > 0; s >>= 1)
            if (tkey[r + s - 1] < xv) r += s;

        // gather lane's pair-dwords: Sw tiles at uint4 idx q, 4+q; Sb at 8+q, 12+q
        const int ro = r * ROW4;
        u32x4 SW0 = SP4[ro + q],     SW1 = SP4[ro + 4 + q];
        u32x4 SB0 = SP4[ro + 8 + q], SB1 = SP4[ro + 12 + q];

        // B-frags: one pk_fma + pk_max per 2 channels, result = frag dword
        const h16x2 xh = {(_Float16)xv, (_Float16)xv};
        u32x4 d0, d1;
        d0.x = pkh2(SW0.x, SB0.x, xh);
        d0.y = pkh2(SW0.y, SB0.y, xh);
        d0.z = pkh2(SW0.z, SB0.z, xh);
        d0.w = pkh2(SW0.w, SB0.w, xh);
        d1.x = pkh2(SW1.x, SB1.x, xh);
        d1.y = pkh2(SW1.y, SB1.y, xh);
        d1.z = pkh2(SW1.z, SB1.z, xh);
        d1.w = pkh2(SW1.w, SB1.w, xh);
        h16x8 bf0 = __builtin_bit_cast(h16x8, d0);
        h16x8 bf1 = __builtin_bit_cast(h16x8, d1);

        // layer 3: D[ch][batch] = W3^T x H2^T (+b3); lane: col=batch n, rows=ch q*4+i
        f32x4 acc0 = {b3c[0], b3c[1], b3c[2], b3c[3]};
        f32x4 acc1 = {b3ch[0], b3ch[1], b3ch[2], b3ch[3]};
        acc0 = __builtin_amdgcn_mfma_f32_16x16x32_f16(aT0lo, bf0, acc0, 0, 0, 0);
        acc0 = __builtin_amdgcn_mfma_f32_16x16x32_f16(aT0hi, bf1, acc0, 0, 0, 0);
        acc1 = __builtin_amdgcn_mfma_f32_16x16x32_f16(aT1lo, bf0, acc1, 0, 0, 0);
        acc1 = __builtin_amdgcn_mfma_f32_16x16x32_f16(aT1hi, bf1, acc1, 0, 0, 0);

        // layer 4: reduce over the lane's OWN 8 channels, then 2 shfls over q
        float p = fmaxf(acc0[0], 0.0f) * w4c[0] + fmaxf(acc1[0], 0.0f) * w4ch[0]
                + fmaxf(acc0[1], 0.0f) * w4c[1] + fmaxf(acc1[1], 0.0f) * w4ch[1]
                + fmaxf(acc0[2], 0.0f) * w4c[2] + fmaxf(acc1[2], 0.0f) * w4ch[2]
                + fmaxf(acc0[3], 0.0f) * w4c[3] + fmaxf(acc1[3], 0.0f) * w4ch[3];
        p += __shfl_xor(p, 16);
        p += __shfl_xor(p, 32);
        if (lane < 16) atomicAdd(&out[base + lane], p + b4f);
    }
}

extern "C" void kernel_launch(void* const* d_in, const int* in_sizes, int n_in,
                              void* d_out, int out_size, void* d_ws, size_t ws_size,
                              hipStream_t stream) {
    const float* x    = (const float*)d_in[0];
    const float* W1   = (const float*)d_in[1];
    const float* b1   = (const float*)d_in[2];
    const float* W2   = (const float*)d_in[3];
    const float* b2   = (const float*)d_in[4];
    const float* W3   = (const float*)d_in[5];
    const float* b3   = (const float*)d_in[6];
    const float* W4   = (const float*)d_in[7];
    const float* b4   = (const float*)d_in[8];
    const float* bias = (const float*)d_in[9];
    float* out = (float*)d_out;

    // d_out is poisoned before every launch: initialize to bias (atomics add onto it)
    init_out_kernel<<<NB / 256, 256, 0, stream>>>(out, bias);
    // grid 512 = (feature, batch-half): 45.6 KB LDS -> 2 blocks/CU, 32 waves/CU
    nam_fused<<<NF * 2, 1024, 0, stream>>>(x, W1, b1, W2, b2,
                                           W3, b3, W4, b4, out);
}